// Round 1
// baseline (143.121 us; speedup 1.0000x reference)
//
#include <hip/hip_runtime.h>
#include <hip/hip_bf16.h>

// Problem constants
#define B_  2
#define L_  2048
#define C_  1024
#define H_  16
#define K_  32
#define DH_ 64
#define M_  (B_ * L_)   // 4096 rows in all GEMMs

typedef __hip_bfloat16 bf16;
typedef __attribute__((ext_vector_type(4))) float f32x4;
typedef __attribute__((ext_vector_type(8))) short short8;
typedef __attribute__((ext_vector_type(8))) unsigned short u16x8;

__device__ inline unsigned short f2bf(float f) {
    __hip_bfloat16 h = __float2bfloat16(f);  // RTN
    return *reinterpret_cast<unsigned short*>(&h);
}
__device__ inline float bf2f(unsigned short u) {
    return __uint_as_float(((unsigned)u) << 16);
}
__device__ inline void gld_lds16(const bf16* g, bf16* l) {
    __builtin_amdgcn_global_load_lds(
        (const __attribute__((address_space(1))) void*)g,
        (__attribute__((address_space(3))) void*)l,
        16, 0, 0);
}

// ---------------------------------------------------------------------------
// Kernel 1: convert x, Wq, Wk, Wv, Wo from f32 to bf16 (one fused launch).
// float4-unit ranges: x=1048576, each W=262144. total 2097152 -> 8192 blocks.
// ---------------------------------------------------------------------------
__global__ void __launch_bounds__(256) cvt_all(
    const float* __restrict__ x,  const float* __restrict__ wq,
    const float* __restrict__ wk, const float* __restrict__ wv,
    const float* __restrict__ wo,
    bf16* __restrict__ xb,  bf16* __restrict__ wqb, bf16* __restrict__ wkb,
    bf16* __restrict__ wvb, bf16* __restrict__ wob)
{
    int g = blockIdx.x * 256 + threadIdx.x;
    const float* src; bf16* dst; int o;
    if (g < 1048576)      { src = x;  dst = xb;  o = g; }
    else if (g < 1310720) { src = wq; dst = wqb; o = g - 1048576; }
    else if (g < 1572864) { src = wk; dst = wkb; o = g - 1310720; }
    else if (g < 1835008) { src = wv; dst = wvb; o = g - 1572864; }
    else                  { src = wo; dst = wob; o = g - 1835008; }
    float4 f = reinterpret_cast<const float4*>(src)[o];
    ushort4 u;
    u.x = f2bf(f.x); u.y = f2bf(f.y); u.z = f2bf(f.z); u.w = f2bf(f.w);
    reinterpret_cast<ushort4*>(dst)[o] = u;
}

// ---------------------------------------------------------------------------
// Kernel 2/4: NT GEMM  Y = A @ W^T  (A: [4096][1024] bf16, W: [1024][1024] bf16)
// 128x128 tile, BK=64, 4 waves each computing 64x64 via 4x4 frags of 16x16x32.
// global_load_lds(16B) staging with both-sides XOR swizzle (rule #21):
// pre-swizzled global source, linear LDS dest, swizzled ds_read.
// MODE: OUT_F32=0 -> bf16 outputs (QKV, seg-selected weight, q scaled 0.125)
//       OUT_F32=1 -> f32 output (final projection to d_out)
// ---------------------------------------------------------------------------
struct GemmArgs {
    const bf16* A;
    const bf16* W[3];
    bf16* Yb[3];
    float* Yf;
    float scale0;
};

template<int OUT_F32>
__global__ void __launch_bounds__(256) gemm_nt(GemmArgs ga)
{
    __shared__ bf16 As[128 * 64];   // 16 KiB
    __shared__ bf16 Bs[128 * 64];   // 16 KiB

    const int m0  = blockIdx.x * 128;
    const int nt  = blockIdx.y;
    const int seg = nt >> 3;            // 0..2 (always 0 for OUT_F32)
    const int n0  = (nt & 7) * 128;
    const bf16* __restrict__ A = ga.A;
    const bf16* __restrict__ W = ga.W[seg];
    const float scale = (seg == 0) ? ga.scale0 : 1.0f;

    const int t    = threadIdx.x;
    const int lane = t & 63;
    const int w    = t >> 6;    // wave 0..3
    const int wm   = w >> 1;    // 0..1
    const int wn   = w & 1;     // 0..1

    const int subrow = lane >> 3;   // 0..7 within an 8-row staging inst
    const int kc     = lane & 7;    // 16B chunk 0..7 within a 64-elem k row

    f32x4 acc[4][4] = {};

    for (int kt = 0; kt < 16; ++kt) {
        const int k0 = kt * 64;
        if (kt) __syncthreads();
        // stage A tile: wave w covers rows [w*32, w*32+32), 4 insts x 8 rows
        #pragma unroll
        for (int i = 0; i < 4; ++i) {
            const int r0  = w * 32 + i * 8;
            const int row = r0 + subrow;
            const int kcs = kc ^ (subrow & 7);   // inverse swizzle on source
            gld_lds16(A + (size_t)(m0 + row) * 1024 + k0 + kcs * 8, As + r0 * 64);
        }
        #pragma unroll
        for (int i = 0; i < 4; ++i) {
            const int r0  = w * 32 + i * 8;
            const int row = r0 + subrow;
            const int kcs = kc ^ (subrow & 7);
            gld_lds16(W + (size_t)(n0 + row) * 1024 + k0 + kcs * 8, Bs + r0 * 64);
        }
        __syncthreads();
        #pragma unroll
        for (int ks = 0; ks < 2; ++ks) {
            short8 af[4], bfv[4];
            #pragma unroll
            for (int mf = 0; mf < 4; ++mf) {
                const int row    = wm * 64 + mf * 16 + (lane & 15);
                const int kchunk = ks * 4 + (lane >> 4);
                const int pc     = kchunk ^ (row & 7);   // swizzled read
                af[mf] = *reinterpret_cast<const short8*>(As + row * 64 + pc * 8);
            }
            #pragma unroll
            for (int nf = 0; nf < 4; ++nf) {
                const int row    = wn * 64 + nf * 16 + (lane & 15);
                const int kchunk = ks * 4 + (lane >> 4);
                const int pc     = kchunk ^ (row & 7);
                bfv[nf] = *reinterpret_cast<const short8*>(Bs + row * 64 + pc * 8);
            }
            #pragma unroll
            for (int mf = 0; mf < 4; ++mf)
                #pragma unroll
                for (int nf = 0; nf < 4; ++nf)
                    acc[mf][nf] = __builtin_amdgcn_mfma_f32_16x16x32_bf16(
                        af[mf], bfv[nf], acc[mf][nf], 0, 0, 0);
        }
    }

    // epilogue: C/D layout col=lane&15, row=(lane>>4)*4+r (verified m89/m91)
    #pragma unroll
    for (int mf = 0; mf < 4; ++mf) {
        #pragma unroll
        for (int nf = 0; nf < 4; ++nf) {
            const int row = m0 + wm * 64 + mf * 16 + ((lane >> 4) << 2);
            const int col = n0 + wn * 64 + nf * 16 + (lane & 15);
            #pragma unroll
            for (int r = 0; r < 4; ++r) {
                const float val = acc[mf][nf][r] * scale;
                if constexpr (OUT_F32) {
                    ga.Yf[(size_t)(row + r) * 1024 + col] = val;
                } else {
                    ga.Yb[seg][(size_t)(row + r) * 1024 + col] = __float2bfloat16(val);
                }
            }
        }
    }
}

// ---------------------------------------------------------------------------
// Kernel 3: K=32 random-neighbor attention. One block per (b, l), 256 threads.
// Layouts (all [B][L][C] with C = h*64+d):
//   QK: thread (h = t>>4, sl = t&15) owns neighbors {sl, sl+16}; each dot reads
//       one 128B line of k. Softmax via __shfl_xor width 16. p -> LDS.
//   PV: thread (h, sl) owns d = sl*4..sl*4+3; per neighbor the wave reads a
//       contiguous 512B span of v. Output bf16 to ao.
// ---------------------------------------------------------------------------
__global__ void __launch_bounds__(256) attn_knn(
    const bf16* __restrict__ qg, const bf16* __restrict__ kg,
    const bf16* __restrict__ vg, const int* __restrict__ idx,
    bf16* __restrict__ ao)
{
    const int l = blockIdx.x;
    const int b = blockIdx.y;
    __shared__ unsigned short q_lds[C_];
    __shared__ int idx_lds[K_];
    __shared__ float p_lds[H_ * K_];

    const int t = threadIdx.x;
    reinterpret_cast<ushort4*>(q_lds)[t] =
        reinterpret_cast<const ushort4*>(qg + ((size_t)b * L_ + l) * C_)[t];
    if (t < K_) idx_lds[t] = idx[l * K_ + t];
    __syncthreads();

    const int h  = t >> 4;
    const int sl = t & 15;

    // ---- QK^T (q already scaled by 1/8) ----
    float s0 = 0.f, s1 = 0.f;
    const unsigned short* qp = q_lds + h * DH_;
    #pragma unroll
    for (int rep = 0; rep < 2; ++rep) {
        const int j   = sl + rep * 16;
        const int row = idx_lds[j];
        const unsigned short* kp =
            reinterpret_cast<const unsigned short*>(kg) + ((size_t)b * L_ + row) * C_ + h * DH_;
        float acc = 0.f;
        #pragma unroll
        for (int c = 0; c < 8; ++c) {
            u16x8 kv = *reinterpret_cast<const u16x8*>(kp + c * 8);
            u16x8 qv = *reinterpret_cast<const u16x8*>(qp + c * 8);
            #pragma unroll
            for (int e = 0; e < 8; ++e) acc += bf2f(qv[e]) * bf2f(kv[e]);
        }
        if (rep == 0) s0 = acc; else s1 = acc;
    }

    // ---- softmax over 32 neighbors (16 lanes x 2 each) ----
    float m = fmaxf(s0, s1);
    #pragma unroll
    for (int o = 8; o >= 1; o >>= 1) m = fmaxf(m, __shfl_xor(m, o, 16));
    float e0 = expf(s0 - m), e1 = expf(s1 - m);
    float ssum = e0 + e1;
    #pragma unroll
    for (int o = 8; o >= 1; o >>= 1) ssum += __shfl_xor(ssum, o, 16);
    const float inv = 1.0f / ssum;
    p_lds[h * K_ + sl]      = e0 * inv;
    p_lds[h * K_ + sl + 16] = e1 * inv;
    __syncthreads();

    // ---- PV ----
    const int d0 = sl * 4;
    float a0 = 0.f, a1 = 0.f, a2 = 0.f, a3 = 0.f;
    #pragma unroll 4
    for (int j = 0; j < K_; ++j) {
        const float p  = p_lds[h * K_ + j];
        const int row  = idx_lds[j];
        const unsigned short* vp =
            reinterpret_cast<const unsigned short*>(vg) + ((size_t)b * L_ + row) * C_ + h * DH_ + d0;
        ushort4 vv = *reinterpret_cast<const ushort4*>(vp);
        a0 += p * bf2f(vv.x);
        a1 += p * bf2f(vv.y);
        a2 += p * bf2f(vv.z);
        a3 += p * bf2f(vv.w);
    }
    ushort4 o4;
    o4.x = f2bf(a0); o4.y = f2bf(a1); o4.z = f2bf(a2); o4.w = f2bf(a3);
    *reinterpret_cast<ushort4*>(ao + ((size_t)b * L_ + l) * C_ + h * DH_ + d0) = o4;
}

// ---------------------------------------------------------------------------
// Launcher. Workspace layout (bytes):
//   xb 0 (8 MiB) | wqb 8M | wkb 10M | wvb 12M | wob 14M (2 MiB each)
//   q 16M | k 24M | v 32M | ao 40M  (8 MiB each)  -> total 48 MiB
// ---------------------------------------------------------------------------
extern "C" void kernel_launch(void* const* d_in, const int* in_sizes, int n_in,
                              void* d_out, int out_size, void* d_ws, size_t ws_size,
                              hipStream_t stream)
{
    const float* x  = (const float*)d_in[0];
    const int*   idx = (const int*)d_in[1];
    const float* Wq = (const float*)d_in[2];
    const float* Wk = (const float*)d_in[3];
    const float* Wv = (const float*)d_in[4];
    const float* Wo = (const float*)d_in[5];
    float* out = (float*)d_out;

    char* ws = (char*)d_ws;
    bf16* xb  = (bf16*)(ws + 0);
    bf16* wqb = (bf16*)(ws + 8388608);
    bf16* wkb = (bf16*)(ws + 10485760);
    bf16* wvb = (bf16*)(ws + 12582912);
    bf16* wob = (bf16*)(ws + 14680064);
    bf16* qb  = (bf16*)(ws + 16777216);
    bf16* kb  = (bf16*)(ws + 25165824);
    bf16* vb  = (bf16*)(ws + 33554432);
    bf16* ab  = (bf16*)(ws + 41943040);

    cvt_all<<<8192, 256, 0, stream>>>(x, Wq, Wk, Wv, Wo, xb, wqb, wkb, wvb, wob);

    GemmArgs g1;
    g1.A = xb;
    g1.W[0] = wqb; g1.W[1] = wkb; g1.W[2] = wvb;
    g1.Yb[0] = qb; g1.Yb[1] = kb; g1.Yb[2] = vb;
    g1.Yf = nullptr;
    g1.scale0 = 0.125f;   // 1/sqrt(Dh)
    gemm_nt<0><<<dim3(32, 24), 256, 0, stream>>>(g1);

    attn_knn<<<dim3(L_, B_), 256, 0, stream>>>(qb, kb, vb, idx, ab);

    GemmArgs g2;
    g2.A = ab;
    g2.W[0] = wob; g2.W[1] = wob; g2.W[2] = wob;
    g2.Yb[0] = nullptr; g2.Yb[1] = nullptr; g2.Yb[2] = nullptr;
    g2.Yf = out;
    g2.scale0 = 1.0f;
    gemm_nt<1><<<dim3(32, 8), 256, 0, stream>>>(g2);
}

// Round 2
// 87.961 us; speedup vs baseline: 1.6271x; 1.6271x over previous
//
#include <hip/hip_runtime.h>
#include <hip/hip_bf16.h>

// Problem constants
#define B_  2
#define L_  2048
#define C_  1024
#define H_  16
#define K_  32
#define DH_ 64
#define M_  (B_ * L_)   // 4096 rows in all GEMMs

typedef __hip_bfloat16 bf16;
typedef __attribute__((ext_vector_type(4))) float f32x4;
typedef __attribute__((ext_vector_type(8))) short short8;
typedef __attribute__((ext_vector_type(8))) unsigned short u16x8;

__device__ inline unsigned short f2bf(float f) {
    __hip_bfloat16 h = __float2bfloat16(f);  // RTN
    return *reinterpret_cast<unsigned short*>(&h);
}
__device__ inline float bf2f(unsigned short u) {
    return __uint_as_float(((unsigned)u) << 16);
}
__device__ inline void gld_lds16(const bf16* g, bf16* l) {
    __builtin_amdgcn_global_load_lds(
        (const __attribute__((address_space(1))) void*)g,
        (__attribute__((address_space(3))) void*)l,
        16, 0, 0);
}

// ---------------------------------------------------------------------------
// Kernel 1: convert x, Wq, Wk, Wv, Wo from f32 to bf16 (one fused launch).
// ---------------------------------------------------------------------------
__global__ void __launch_bounds__(256) cvt_all(
    const float* __restrict__ x,  const float* __restrict__ wq,
    const float* __restrict__ wk, const float* __restrict__ wv,
    const float* __restrict__ wo,
    bf16* __restrict__ xb,  bf16* __restrict__ wqb, bf16* __restrict__ wkb,
    bf16* __restrict__ wvb, bf16* __restrict__ wob)
{
    int g = blockIdx.x * 256 + threadIdx.x;
    const float* src; bf16* dst; int o;
    if (g < 1048576)      { src = x;  dst = xb;  o = g; }
    else if (g < 1310720) { src = wq; dst = wqb; o = g - 1048576; }
    else if (g < 1572864) { src = wk; dst = wkb; o = g - 1310720; }
    else if (g < 1835008) { src = wv; dst = wvb; o = g - 1572864; }
    else                  { src = wo; dst = wob; o = g - 1835008; }
    float4 f = reinterpret_cast<const float4*>(src)[o];
    ushort4 u;
    u.x = f2bf(f.x); u.y = f2bf(f.y); u.z = f2bf(f.z); u.w = f2bf(f.w);
    reinterpret_cast<ushort4*>(dst)[o] = u;
}

// ---------------------------------------------------------------------------
// Kernel 2/4: NT GEMM  Y = A @ W^T  (A: [4096][1024] bf16, W: [1024][1024] bf16)
// 128x128 tile, BK=64, 4 waves x (4x4) frags of 16x16x32 bf16 MFMA.
// global_load_lds(16B) with both-sides XOR swizzle (pre-swizzled source +
// swizzled ds_read; LDS dest stays linear).
// ---------------------------------------------------------------------------
struct GemmArgs {
    const bf16* A;
    const bf16* W[3];
    bf16* Yb[3];
    float* Yf;
    float scale0;
};

template<int OUT_F32>
__global__ void __launch_bounds__(256) gemm_nt(GemmArgs ga)
{
    __shared__ bf16 As[128 * 64];   // 16 KiB
    __shared__ bf16 Bs[128 * 64];   // 16 KiB

    const int m0  = blockIdx.x * 128;
    const int nt  = blockIdx.y;
    const int seg = nt >> 3;            // 0..2 (always 0 for OUT_F32)
    const int n0  = (nt & 7) * 128;
    const bf16* __restrict__ A = ga.A;
    const bf16* __restrict__ W = ga.W[seg];
    const float scale = (seg == 0) ? ga.scale0 : 1.0f;

    const int t    = threadIdx.x;
    const int lane = t & 63;
    const int w    = t >> 6;    // wave 0..3
    const int wm   = w >> 1;    // 0..1
    const int wn   = w & 1;     // 0..1

    const int subrow = lane >> 3;   // 0..7 within an 8-row staging inst
    const int kc     = lane & 7;    // 16B chunk 0..7 within a 64-elem k row

    f32x4 acc[4][4] = {};

    for (int kt = 0; kt < 16; ++kt) {
        const int k0 = kt * 64;
        if (kt) __syncthreads();
        #pragma unroll
        for (int i = 0; i < 4; ++i) {
            const int r0  = w * 32 + i * 8;
            const int row = r0 + subrow;
            const int kcs = kc ^ (subrow & 7);   // inverse swizzle on source
            gld_lds16(A + (size_t)(m0 + row) * 1024 + k0 + kcs * 8, As + r0 * 64);
        }
        #pragma unroll
        for (int i = 0; i < 4; ++i) {
            const int r0  = w * 32 + i * 8;
            const int row = r0 + subrow;
            const int kcs = kc ^ (subrow & 7);
            gld_lds16(W + (size_t)(n0 + row) * 1024 + k0 + kcs * 8, Bs + r0 * 64);
        }
        __syncthreads();
        #pragma unroll
        for (int ks = 0; ks < 2; ++ks) {
            short8 af[4], bfv[4];
            #pragma unroll
            for (int mf = 0; mf < 4; ++mf) {
                const int row    = wm * 64 + mf * 16 + (lane & 15);
                const int kchunk = ks * 4 + (lane >> 4);
                const int pc     = kchunk ^ (row & 7);   // swizzled read
                af[mf] = *reinterpret_cast<const short8*>(As + row * 64 + pc * 8);
            }
            #pragma unroll
            for (int nf = 0; nf < 4; ++nf) {
                const int row    = wn * 64 + nf * 16 + (lane & 15);
                const int kchunk = ks * 4 + (lane >> 4);
                const int pc     = kchunk ^ (row & 7);
                bfv[nf] = *reinterpret_cast<const short8*>(Bs + row * 64 + pc * 8);
            }
            #pragma unroll
            for (int mf = 0; mf < 4; ++mf)
                #pragma unroll
                for (int nf = 0; nf < 4; ++nf)
                    acc[mf][nf] = __builtin_amdgcn_mfma_f32_16x16x32_bf16(
                        af[mf], bfv[nf], acc[mf][nf], 0, 0, 0);
        }
    }

    #pragma unroll
    for (int mf = 0; mf < 4; ++mf) {
        #pragma unroll
        for (int nf = 0; nf < 4; ++nf) {
            const int row = m0 + wm * 64 + mf * 16 + ((lane >> 4) << 2);
            const int col = n0 + wn * 64 + nf * 16 + (lane & 15);
            #pragma unroll
            for (int r = 0; r < 4; ++r) {
                const float val = acc[mf][nf][r] * scale;
                if constexpr (OUT_F32) {
                    ga.Yf[(size_t)(row + r) * 1024 + col] = val;
                } else {
                    ga.Yb[seg][(size_t)(row + r) * 1024 + col] = __float2bfloat16(val);
                }
            }
        }
    }
}

// ---------------------------------------------------------------------------
// Kernel 3: K=32 neighbor attention — fully wave-synchronous, no LDS, no
// barriers. One 64-lane wave per (b, l, head-group-of-4).
//   lane = (hw<<4) | (half<<3) | c8 ;  h = wg*4+hw ; d-chunk = c8*8 (16B)
//   QK: lane loads k[idx[half*16+jj]] chunk c8, partial dot with q chunk c8,
//       8-lane shfl_xor reduce -> every lane holds s[half*16 + 0..16).
//   softmax in registers (max/sum + one cross-half shfl); 1/sum folded into
//   the final store scale.
//   PV: lane accumulates its 16B v-chunk over its half's 16 neighbors,
//       cross-half shfl_xor combine, half==0 lanes store 16B.
// All 16 k loads and all 16 v loads are independent -> deep MLP per wave.
// ---------------------------------------------------------------------------
__global__ void __launch_bounds__(64) attn_knn(
    const bf16* __restrict__ qg, const bf16* __restrict__ kg,
    const bf16* __restrict__ vg, const int* __restrict__ idx,
    bf16* __restrict__ ao)
{
    const int wb = blockIdx.x;        // b*4 + wg
    const int l  = blockIdx.y;
    const int b  = wb >> 2;
    const int wg = wb & 3;

    const int lane = threadIdx.x;     // 0..63
    const int hw   = lane >> 4;       // head within group
    const int h    = wg * 4 + hw;
    const int sl   = lane & 15;
    const int half = sl >> 3;
    const int c8   = sl & 7;

    const size_t rowq = (size_t)b * L_ + l;
    const unsigned short* kg16 = reinterpret_cast<const unsigned short*>(kg);
    const unsigned short* vg16 = reinterpret_cast<const unsigned short*>(vg);

    // neighbor indices for this half (16 ints, 4x int4, L2-hot)
    int4 iv[4];
    #pragma unroll
    for (int i = 0; i < 4; ++i)
        iv[i] = reinterpret_cast<const int4*>(idx + l * K_ + half * 16)[i];

    // q chunk (16B) for (h, c8) — q already scaled by 1/8 in the QKV GEMM
    u16x8 qv = *reinterpret_cast<const u16x8*>(
        reinterpret_cast<const unsigned short*>(qg) + rowq * C_ + h * DH_ + c8 * 8);
    float qf[8];
    #pragma unroll
    for (int e = 0; e < 8; ++e) qf[e] = bf2f(qv[e]);

    // ---- QK^T partial dots (16 independent 16B gathers) ----
    float s[16];
    #pragma unroll
    for (int jj = 0; jj < 16; ++jj) {
        const int4 q4 = iv[jj >> 2];
        const int row = (jj & 3) == 0 ? q4.x : (jj & 3) == 1 ? q4.y
                       : (jj & 3) == 2 ? q4.z : q4.w;
        const u16x8 kv = *reinterpret_cast<const u16x8*>(
            kg16 + ((size_t)b * L_ + row) * C_ + h * DH_ + c8 * 8);
        float acc = 0.f;
        #pragma unroll
        for (int e = 0; e < 8; ++e) acc += qf[e] * bf2f(kv[e]);
        s[jj] = acc;
    }

    // reduce partial dots across the 8-lane c8 group
    #pragma unroll
    for (int jj = 0; jj < 16; ++jj) {
        float x = s[jj];
        x += __shfl_xor(x, 1, 16);
        x += __shfl_xor(x, 2, 16);
        x += __shfl_xor(x, 4, 16);
        s[jj] = x;   // full score for j = half*16 + jj, in all 8 lanes
    }

    // ---- softmax (in registers; 1/sum deferred to the store) ----
    float m = s[0];
    #pragma unroll
    for (int jj = 1; jj < 16; ++jj) m = fmaxf(m, s[jj]);
    m = fmaxf(m, __shfl_xor(m, 8, 16));
    float ssum = 0.f;
    #pragma unroll
    for (int jj = 0; jj < 16; ++jj) { s[jj] = __expf(s[jj] - m); ssum += s[jj]; }
    ssum += __shfl_xor(ssum, 8, 16);
    const float inv = 1.0f / ssum;

    // ---- PV (16 independent 16B gathers, weights in-register) ----
    float acc[8] = {0.f, 0.f, 0.f, 0.f, 0.f, 0.f, 0.f, 0.f};
    #pragma unroll
    for (int jj = 0; jj < 16; ++jj) {
        const int4 q4 = iv[jj >> 2];
        const int row = (jj & 3) == 0 ? q4.x : (jj & 3) == 1 ? q4.y
                       : (jj & 3) == 2 ? q4.z : q4.w;
        const u16x8 vv = *reinterpret_cast<const u16x8*>(
            vg16 + ((size_t)b * L_ + row) * C_ + h * DH_ + c8 * 8);
        const float p = s[jj];
        #pragma unroll
        for (int e = 0; e < 8; ++e) acc[e] += p * bf2f(vv[e]);
    }
    #pragma unroll
    for (int e = 0; e < 8; ++e) acc[e] += __shfl_xor(acc[e], 8, 16);

    if (half == 0) {
        u16x8 o;
        #pragma unroll
        for (int e = 0; e < 8; ++e) o[e] = f2bf(acc[e] * inv);
        *reinterpret_cast<u16x8*>(ao + rowq * C_ + h * DH_ + c8 * 8) = o;
    }
}

// ---------------------------------------------------------------------------
// Launcher. Workspace layout (bytes):
//   xb 0 (8 MiB) | wqb 8M | wkb 10M | wvb 12M | wob 14M (2 MiB each)
//   q 16M | k 24M | v 32M | ao 40M  (8 MiB each)  -> total 48 MiB
// ---------------------------------------------------------------------------
extern "C" void kernel_launch(void* const* d_in, const int* in_sizes, int n_in,
                              void* d_out, int out_size, void* d_ws, size_t ws_size,
                              hipStream_t stream)
{
    const float* x  = (const float*)d_in[0];
    const int*   idx = (const int*)d_in[1];
    const float* Wq = (const float*)d_in[2];
    const float* Wk = (const float*)d_in[3];
    const float* Wv = (const float*)d_in[4];
    const float* Wo = (const float*)d_in[5];
    float* out = (float*)d_out;

    char* ws = (char*)d_ws;
    bf16* xb  = (bf16*)(ws + 0);
    bf16* wqb = (bf16*)(ws + 8388608);
    bf16* wkb = (bf16*)(ws + 10485760);
    bf16* wvb = (bf16*)(ws + 12582912);
    bf16* wob = (bf16*)(ws + 14680064);
    bf16* qb  = (bf16*)(ws + 16777216);
    bf16* kb  = (bf16*)(ws + 25165824);
    bf16* vb  = (bf16*)(ws + 33554432);
    bf16* ab  = (bf16*)(ws + 41943040);

    cvt_all<<<8192, 256, 0, stream>>>(x, Wq, Wk, Wv, Wo, xb, wqb, wkb, wvb, wob);

    GemmArgs g1;
    g1.A = xb;
    g1.W[0] = wqb; g1.W[1] = wkb; g1.W[2] = wvb;
    g1.Yb[0] = qb; g1.Yb[1] = kb; g1.Yb[2] = vb;
    g1.Yf = nullptr;
    g1.scale0 = 0.125f;   // 1/sqrt(Dh)
    gemm_nt<0><<<dim3(32, 24), 256, 0, stream>>>(g1);

    attn_knn<<<dim3(8, L_), 64, 0, stream>>>(qb, kb, vb, idx, ab);

    GemmArgs g2;
    g2.A = ab;
    g2.W[0] = wob; g2.W[1] = wob; g2.W[2] = wob;
    g2.Yb[0] = nullptr; g2.Yb[1] = nullptr; g2.Yb[2] = nullptr;
    g2.Yf = out;
    g2.scale0 = 1.0f;
    gemm_nt<1><<<dim3(32, 8), 256, 0, stream>>>(g2);
}